// Round 2
// baseline (1903.205 us; speedup 1.0000x reference)
//
#include <hip/hip_runtime.h>

#define HID 256
#define HHALF 128
#define LDS_STRIDE 68   // 64 + 4 pad: 16B-aligned float4 rows, bank-conflict-light

// ---------------- CSR build ----------------
__global__ void k_count(const int* __restrict__ dst, int* __restrict__ cnt, int E) {
    int i = blockIdx.x * blockDim.x + threadIdx.x;
    if (i < E) atomicAdd(&cnt[dst[i]], 1);
}

__global__ void k_scan_block(const int* __restrict__ cnt, int* __restrict__ bsum, int n) {
    __shared__ int sd[256];
    int tid = threadIdx.x;
    int i = blockIdx.x * 256 + tid;
    int v = (i < n) ? cnt[i] : 0;
    sd[tid] = v; __syncthreads();
    for (int s = 128; s > 0; s >>= 1) {
        if (tid < s) sd[tid] += sd[tid + s];
        __syncthreads();
    }
    if (tid == 0) bsum[blockIdx.x] = sd[0];
}

__global__ void k_scan_top(int* __restrict__ bsum, int nb) {
    __shared__ int sd[512];
    int t = threadIdx.x;
    int v = (t < nb) ? bsum[t] : 0;
    sd[t] = v; __syncthreads();
    for (int s = 1; s < 512; s <<= 1) {
        int x = (t >= s) ? sd[t - s] : 0;
        __syncthreads();
        sd[t] += x;
        __syncthreads();
    }
    if (t < nb) bsum[t] = sd[t] - v;  // exclusive
}

__global__ void k_scan_down(const int* __restrict__ cnt, const int* __restrict__ boff,
                            int* __restrict__ row_off, int n, int total) {
    __shared__ int sd[256];
    int tid = threadIdx.x;
    int i = blockIdx.x * 256 + tid;
    int v = (i < n) ? cnt[i] : 0;
    sd[tid] = v; __syncthreads();
    for (int s = 1; s < 256; s <<= 1) {
        int x = (tid >= s) ? sd[tid - s] : 0;
        __syncthreads();
        sd[tid] += x;
        __syncthreads();
    }
    if (i < n) row_off[i] = boff[blockIdx.x] + sd[tid] - v;
    if (i == 0) row_off[n] = total;
}

__global__ void k_scatter(const int* __restrict__ src, const int* __restrict__ dst,
                          const int* __restrict__ row_off, int* __restrict__ fill,
                          int* __restrict__ col, int E) {
    int i = blockIdx.x * blockDim.x + threadIdx.x;
    if (i < E) {
        int d = dst[i];
        int p = atomicAdd(&fill[d], 1);
        col[row_off[d] + p] = src[i];
    }
}

// ---------------- mean aggregation: msg[n] = mean over in-neighbors of h ----------------
__global__ void k_agg(const float* __restrict__ h, const int* __restrict__ row_off,
                      const int* __restrict__ col, float* __restrict__ msg, int n) {
    int node = blockIdx.x;
    if (node >= n) return;
    int t = threadIdx.x;
    int s0 = row_off[node], s1 = row_off[node + 1];
    float acc = 0.f;
    for (int e = s0; e < s1; ++e) {
        int c = col[e];
        acc += h[(size_t)c * HID + t];
    }
    int deg = s1 - s0;
    float inv = 1.0f / (float)(deg > 1 ? deg : 1);
    msg[(size_t)node * HID + t] = acc * inv;
}

// ---------------- fused GEMM: out = relu(A1@W1 [+ A2@W2] + bias), K=256 ----------------
// W row-major [256 x ncols]; out [n x ncols]; ncols in {128, 256} (multiple of 64)
__global__ __launch_bounds__(256) void k_gemm(
    const float* __restrict__ A1, const float* __restrict__ W1,
    const float* __restrict__ A2, const float* __restrict__ W2,
    const float* __restrict__ bias, float* __restrict__ out,
    int n, int ncols) {
    __shared__ float As[16 * LDS_STRIDE];
    __shared__ float Bs[16 * LDS_STRIDE];
    int tid = threadIdx.x;
    int tx = tid & 15, ty = tid >> 4;
    int brow = blockIdx.x * 64;
    int bcol = blockIdx.y * 64;
    float acc[4][4] = {};
    int lr = tid >> 2;            // 0..63 : A row within tile
    int lk = (tid & 3) * 4;       // k quad for A staging
    int bk = tid >> 4;            // 0..15 : k for B staging
    int bc = (tid & 15) * 4;      // col quad for B staging
    int arow = brow + lr;
    bool arow_ok = arow < n;

    for (int phase = 0; phase < 2; ++phase) {
        const float* A = phase ? A2 : A1;
        const float* W = phase ? W2 : W1;
        if (!A) break;
        for (int kt = 0; kt < 16; ++kt) {
            __syncthreads();
            float4 av = make_float4(0.f, 0.f, 0.f, 0.f);
            if (arow_ok) av = *(const float4*)&A[(size_t)arow * HID + kt * 16 + lk];
            As[(lk + 0) * LDS_STRIDE + lr] = av.x;
            As[(lk + 1) * LDS_STRIDE + lr] = av.y;
            As[(lk + 2) * LDS_STRIDE + lr] = av.z;
            As[(lk + 3) * LDS_STRIDE + lr] = av.w;
            float4 bv = *(const float4*)&W[(size_t)(kt * 16 + bk) * ncols + bcol + bc];
            *(float4*)&Bs[bk * LDS_STRIDE + bc] = bv;
            __syncthreads();
            #pragma unroll
            for (int k = 0; k < 16; ++k) {
                float4 a = *(float4*)&As[k * LDS_STRIDE + ty * 4];
                float4 b = *(float4*)&Bs[k * LDS_STRIDE + tx * 4];
                float ar[4] = {a.x, a.y, a.z, a.w};
                float br[4] = {b.x, b.y, b.z, b.w};
                #pragma unroll
                for (int i = 0; i < 4; ++i)
                    #pragma unroll
                    for (int j = 0; j < 4; ++j)
                        acc[i][j] = fmaf(ar[i], br[j], acc[i][j]);
            }
        }
    }
    #pragma unroll
    for (int i = 0; i < 4; ++i) {
        int row = brow + ty * 4 + i;
        if (row >= n) continue;
        float4 o;
        o.x = fmaxf(acc[i][0] + bias[bcol + tx * 4 + 0], 0.f);
        o.y = fmaxf(acc[i][1] + bias[bcol + tx * 4 + 1], 0.f);
        o.z = fmaxf(acc[i][2] + bias[bcol + tx * 4 + 2], 0.f);
        o.w = fmaxf(acc[i][3] + bias[bcol + tx * 4 + 3], 0.f);
        *(float4*)&out[(size_t)row * ncols + bcol + tx * 4] = o;
    }
}

// ---------------- attention scores: s = h @ att_w + att_b ----------------
__global__ void k_score(const float* __restrict__ h, const float* __restrict__ att_w,
                        const float* __restrict__ att_b, float* __restrict__ s, int n) {
    int gw = (blockIdx.x * blockDim.x + threadIdx.x) >> 6;
    int lane = threadIdx.x & 63;
    if (gw >= n) return;
    float4 hv = *(const float4*)&h[(size_t)gw * HID + lane * 4];
    float4 wv = *(const float4*)&att_w[lane * 4];
    float p = hv.x * wv.x + hv.y * wv.y + hv.z * wv.z + hv.w * wv.w;
    #pragma unroll
    for (int off = 32; off; off >>= 1) p += __shfl_xor(p, off, 64);
    if (lane == 0) s[gw] = p + att_b[0];
}

// ---------------- graph start offsets from sorted batch ----------------
__global__ void k_gstart(const int* __restrict__ batch, int* __restrict__ gstart, int n, int G) {
    int i = blockIdx.x * blockDim.x + threadIdx.x;
    if (i >= n) return;
    int b = batch[i];
    int bp = (i == 0) ? -1 : batch[i - 1];
    for (int g = bp + 1; g <= b; ++g) gstart[g] = i;
    if (i == n - 1) {
        for (int g = b + 1; g <= G; ++g) gstart[g] = n;
    }
}

// ---------------- per-graph max + softmax denom ----------------
__global__ void k_mdenom(const float* __restrict__ s, const int* __restrict__ gstart,
                         float* __restrict__ m, float* __restrict__ denom) {
    int g = blockIdx.x;
    int t = threadIdx.x;
    int i0 = gstart[g], i1 = gstart[g + 1];
    __shared__ float red[256];
    float mx = -INFINITY;
    for (int i = i0 + t; i < i1; i += 256) mx = fmaxf(mx, s[i]);
    red[t] = mx; __syncthreads();
    for (int st = 128; st; st >>= 1) {
        if (t < st) red[t] = fmaxf(red[t], red[t + st]);
        __syncthreads();
    }
    float gm = red[0];
    __syncthreads();
    float sm = 0.f;
    for (int i = i0 + t; i < i1; i += 256) sm += expf(s[i] - gm);
    red[t] = sm; __syncthreads();
    for (int st = 128; st; st >>= 1) {
        if (t < st) red[t] += red[t + st];
        __syncthreads();
    }
    if (t == 0) { m[g] = gm; denom[g] = red[0]; }
}

__global__ void k_alpha(const float* __restrict__ s, const int* __restrict__ batch,
                        const float* __restrict__ m, const float* __restrict__ denom,
                        float* __restrict__ alpha, int n) {
    int i = blockIdx.x * blockDim.x + threadIdx.x;
    if (i >= n) return;
    int b = batch[i];
    float d = denom[b];
    alpha[i] = (d > 0.f) ? expf(s[i] - m[b]) / d : 0.f;
}

// ---------------- attention pooling: gpool[g] = sum alpha_i * h_i ----------------
__global__ void k_pool(const float* __restrict__ h, const float* __restrict__ alpha,
                       const int* __restrict__ gstart, float* __restrict__ gpool) {
    int g = blockIdx.x, sp = blockIdx.y, t = threadIdx.x;
    int i0 = gstart[g], i1 = gstart[g + 1];
    int len = i1 - i0;
    int a = i0 + (int)((long long)len * sp / 16);
    int b = i0 + (int)((long long)len * (sp + 1) / 16);
    float acc = 0.f;
    for (int i = a; i < b; ++i) acc += alpha[i] * h[(size_t)i * HID + t];
    if (acc != 0.f || sp == 0) atomicAdd(&gpool[g * HID + t], acc);
}

// ---------------- graph head: out[g] = relu(gpool@W1+b1)@W2 + b2 ----------------
__global__ void k_ghead(const float* __restrict__ gpool, const float* __restrict__ W1,
                        const float* __restrict__ b1, const float* __restrict__ W2,
                        const float* __restrict__ b2, float* __restrict__ out) {
    int g = blockIdx.x, t = threadIdx.x;  // 128 threads
    __shared__ float row[HID];
    __shared__ float red[128];
    row[t] = gpool[g * HID + t];
    row[t + 128] = gpool[g * HID + t + 128];
    __syncthreads();
    float acc = 0.f;
    #pragma unroll 8
    for (int k = 0; k < HID; ++k) acc = fmaf(row[k], W1[k * HHALF + t], acc);
    float hid = fmaxf(acc + b1[t], 0.f);
    red[t] = hid * W2[t];
    __syncthreads();
    for (int st = 64; st; st >>= 1) {
        if (t < st) red[t] += red[t + st];
        __syncthreads();
    }
    if (t == 0) out[g] = red[0] + b2[0];
}

// ---------------- node head second layer: out[i] = hid[i]@W2 + b2 ----------------
__global__ void k_ndot(const float* __restrict__ hid, const float* __restrict__ W2,
                       const float* __restrict__ b2, float* __restrict__ out, int n) {
    int gw = (blockIdx.x * blockDim.x + threadIdx.x) >> 6;
    int lane = threadIdx.x & 63;
    if (gw >= n) return;
    float v = hid[(size_t)gw * HHALF + lane] * W2[lane]
            + hid[(size_t)gw * HHALF + 64 + lane] * W2[64 + lane];
    #pragma unroll
    for (int off = 32; off; off >>= 1) v += __shfl_xor(v, off, 64);
    if (lane == 0) out[gw] = v + b2[0];
}

extern "C" void kernel_launch(void* const* d_in, const int* in_sizes, int n_in,
                              void* d_out, int out_size, void* d_ws, size_t ws_size,
                              hipStream_t stream) {
    const float* x      = (const float*)d_in[0];
    const int*   eidx   = (const int*)d_in[1];
    const int*   batch  = (const int*)d_in[2];
    const float* Ws     = (const float*)d_in[3];
    const float* Wn     = (const float*)d_in[4];
    const float* bs     = (const float*)d_in[5];
    const float* att_w  = (const float*)d_in[6];
    const float* att_b  = (const float*)d_in[7];
    const float* ne_W1  = (const float*)d_in[8];
    const float* ne_b1  = (const float*)d_in[9];
    const float* ne_W2  = (const float*)d_in[10];
    const float* ne_b2  = (const float*)d_in[11];
    const float* nd_W1  = (const float*)d_in[12];
    const float* nd_b1  = (const float*)d_in[13];
    const float* nd_W2  = (const float*)d_in[14];
    const float* nd_b2  = (const float*)d_in[15];
    float* out = (float*)d_out;

    const int N = in_sizes[2];
    const int E = in_sizes[1] / 2;
    const int L = in_sizes[3] / (HID * HID);
    const int G = out_size - N;

    const int* src = eidx;
    const int* dst = eidx + E;

    // workspace carve-up
    size_t off = 0;
    auto alloc = [&](size_t bytes) {
        void* p = (char*)d_ws + off;
        off += (bytes + 255) & ~(size_t)255;
        return p;
    };
    int*   cnt     = (int*)alloc((size_t)N * 4);
    int*   row_off = (int*)alloc((size_t)(N + 1) * 4);
    int*   fill    = (int*)alloc((size_t)N * 4);
    int*   col     = (int*)alloc((size_t)E * 4);
    int*   gstart  = (int*)alloc((size_t)(G + 1) * 4);
    int*   bsum    = (int*)alloc(1024 * 4);
    float* sarr    = (float*)alloc((size_t)N * 4);
    float* alpha   = (float*)alloc((size_t)N * 4);
    float* marr    = (float*)alloc((size_t)G * 4);
    float* denom   = (float*)alloc((size_t)G * 4);
    float* gpool   = (float*)alloc((size_t)G * HID * 4);
    float* msg     = (float*)alloc((size_t)N * HID * 4);
    float* h1      = (float*)alloc((size_t)N * HID * 4);
    float* h2      = (float*)alloc((size_t)N * HID * 4);
    (void)ws_size;

    const int eb = (E + 255) / 256;
    const int nb = (N + 255) / 256;

    // ---- CSR build (once; reused across layers) ----
    hipMemsetAsync(cnt, 0, (size_t)N * 4, stream);
    k_count<<<eb, 256, 0, stream>>>(dst, cnt, E);
    k_scan_block<<<nb, 256, 0, stream>>>(cnt, bsum, N);
    k_scan_top<<<1, 512, 0, stream>>>(bsum, nb);
    k_scan_down<<<nb, 256, 0, stream>>>(cnt, bsum, row_off, N, E);
    hipMemsetAsync(fill, 0, (size_t)N * 4, stream);
    k_scatter<<<eb, 256, 0, stream>>>(src, dst, row_off, fill, col, E);

    // ---- GNN layers ----
    const int gx = (N + 63) / 64;
    const float* hin = x;
    float* hout = h1;
    for (int l = 0; l < L; ++l) {
        k_agg<<<N, HID, 0, stream>>>(hin, row_off, col, msg, N);
        k_gemm<<<dim3(gx, HID / 64), 256, 0, stream>>>(
            hin, Ws + (size_t)l * HID * HID, msg, Wn + (size_t)l * HID * HID,
            bs + (size_t)l * HID, hout, N, HID);
        hin = hout;
        hout = (hout == h1) ? h2 : h1;
    }
    const float* h = hin;  // final node embeddings

    // ---- attention pooling ----
    k_score<<<(N + 3) / 4, 256, 0, stream>>>(h, att_w, att_b, sarr, N);
    k_gstart<<<nb, 256, 0, stream>>>(batch, gstart, N, G);
    k_mdenom<<<G, 256, 0, stream>>>(sarr, gstart, marr, denom);
    k_alpha<<<nb, 256, 0, stream>>>(sarr, batch, marr, denom, alpha, N);
    hipMemsetAsync(gpool, 0, (size_t)G * HID * 4, stream);
    k_pool<<<dim3(G, 16), HID, 0, stream>>>(h, alpha, gstart, gpool);

    // ---- graph head ----
    k_ghead<<<G, HHALF, 0, stream>>>(gpool, ne_W1, ne_b1, ne_W2, ne_b2, out);

    // ---- node head: hidden = relu(h @ nd_W1 + b1) (reuse msg buffer), then dot ----
    k_gemm<<<dim3(gx, HHALF / 64), 256, 0, stream>>>(
        h, nd_W1, nullptr, nullptr, nd_b1, msg, N, HHALF);
    k_ndot<<<(N + 3) / 4, 256, 0, stream>>>(msg, nd_W2, nd_b2, out + G, N);
}

// Round 3
// 687.151 us; speedup vs baseline: 2.7697x; 2.7697x over previous
//
#include <hip/hip_runtime.h>
#include <hip/hip_bf16.h>

#define HID 256
#define HHALF 128

typedef unsigned short u16;
typedef __attribute__((ext_vector_type(8))) short bf16x8;
typedef __attribute__((ext_vector_type(4))) float f32x4;

__device__ __forceinline__ float bf2f(unsigned int u) {
    unsigned int x = (u & 0xffffu) << 16;
    union { unsigned int i; float f; } c; c.i = x; return c.f;
}
__device__ __forceinline__ u16 f2bf(float f) {
    __hip_bfloat16 h = __float2bfloat16(f);   // RNE
    union { __hip_bfloat16 h; u16 u; } c; c.h = h; return c.u;
}

// ---------------- CSR build ----------------
__global__ void k_count(const int* __restrict__ dst, int* __restrict__ cnt, int E) {
    int i = blockIdx.x * blockDim.x + threadIdx.x;
    if (i < E) atomicAdd(&cnt[dst[i]], 1);
}

__global__ void k_scan_block(const int* __restrict__ cnt, int* __restrict__ bsum, int n) {
    __shared__ int sd[256];
    int tid = threadIdx.x;
    int i = blockIdx.x * 256 + tid;
    int v = (i < n) ? cnt[i] : 0;
    sd[tid] = v; __syncthreads();
    for (int s = 128; s > 0; s >>= 1) {
        if (tid < s) sd[tid] += sd[tid + s];
        __syncthreads();
    }
    if (tid == 0) bsum[blockIdx.x] = sd[0];
}

__global__ void k_scan_top(int* __restrict__ bsum, int nb) {
    __shared__ int sd[512];
    int t = threadIdx.x;
    int v = (t < nb) ? bsum[t] : 0;
    sd[t] = v; __syncthreads();
    for (int s = 1; s < 512; s <<= 1) {
        int x = (t >= s) ? sd[t - s] : 0;
        __syncthreads();
        sd[t] += x;
        __syncthreads();
    }
    if (t < nb) bsum[t] = sd[t] - v;  // exclusive
}

__global__ void k_scan_down(const int* __restrict__ cnt, const int* __restrict__ boff,
                            int* __restrict__ row_off, int n, int total) {
    __shared__ int sd[256];
    int tid = threadIdx.x;
    int i = blockIdx.x * 256 + tid;
    int v = (i < n) ? cnt[i] : 0;
    sd[tid] = v; __syncthreads();
    for (int s = 1; s < 256; s <<= 1) {
        int x = (tid >= s) ? sd[tid - s] : 0;
        __syncthreads();
        sd[tid] += x;
        __syncthreads();
    }
    if (i < n) row_off[i] = boff[blockIdx.x] + sd[tid] - v;
    if (i == 0) row_off[n] = total;
}

__global__ void k_scatter(const int* __restrict__ src, const int* __restrict__ dst,
                          const int* __restrict__ row_off, int* __restrict__ fill,
                          int* __restrict__ col, int E) {
    int i = blockIdx.x * blockDim.x + threadIdx.x;
    if (i < E) {
        int d = dst[i];
        int p = atomicAdd(&fill[d], 1);
        col[row_off[d] + p] = src[i];
    }
}

// ---------------- conversions ----------------
// fp32 -> bf16, 4 elems/thread
__global__ void k_f2b(const float* __restrict__ in, u16* __restrict__ o, int total4) {
    int i = blockIdx.x * blockDim.x + threadIdx.x;
    if (i >= total4) return;
    float4 v = *(const float4*)&in[(size_t)i * 4];
    uint2 p;
    p.x = (unsigned)f2bf(v.x) | ((unsigned)f2bf(v.y) << 16);
    p.y = (unsigned)f2bf(v.z) | ((unsigned)f2bf(v.w) << 16);
    *(uint2*)&o[(size_t)i * 4] = p;
}

// W [K][C] fp32 -> Wt [C][K] bf16
__global__ void k_wt(const float* __restrict__ W, u16* __restrict__ Wt, int K, int C) {
    int idx = blockIdx.x * blockDim.x + threadIdx.x;
    if (idx >= K * C) return;
    int k = idx / C, c = idx - k * C;
    Wt[c * K + k] = f2bf(W[idx]);
}

// ---------------- mean aggregation (bf16 in/out, fp32 accum) ----------------
// one wave per node; each lane owns 4 channels
__global__ void k_agg(const u16* __restrict__ h, const int* __restrict__ row_off,
                      const int* __restrict__ col, u16* __restrict__ msg, int n) {
    int node = blockIdx.x;
    if (node >= n) return;
    int t = threadIdx.x;  // 0..63
    int s0 = row_off[node], s1 = row_off[node + 1];
    float a0 = 0.f, a1 = 0.f, a2 = 0.f, a3 = 0.f;
    for (int e = s0; e < s1; ++e) {
        int c = col[e];
        uint2 v = *(const uint2*)&h[(size_t)c * HID + t * 4];
        a0 += bf2f(v.x); a1 += bf2f(v.x >> 16);
        a2 += bf2f(v.y); a3 += bf2f(v.y >> 16);
    }
    int deg = s1 - s0;
    float inv = 1.0f / (float)(deg > 1 ? deg : 1);
    uint2 o;
    o.x = (unsigned)f2bf(a0 * inv) | ((unsigned)f2bf(a1 * inv) << 16);
    o.y = (unsigned)f2bf(a2 * inv) | ((unsigned)f2bf(a3 * inv) << 16);
    *(uint2*)&msg[(size_t)node * HID + t * 4] = o;
}

// ---------------- bf16 MFMA GEMM: out = relu(A1@W1 [+ A2@W2] + bias) ----------------
// A: [n][256] bf16 row-major. Wt: [ncols][256] bf16 (pre-transposed). out: [n][ncols] bf16.
// 128x128 tile, 4 waves (2x2), BK=32, 16x16x32 MFMA, m97-style 2-barrier loop.
__global__ __launch_bounds__(256) void k_gemm_bf(
    const u16* __restrict__ A1, const u16* __restrict__ W1t,
    const u16* __restrict__ A2, const u16* __restrict__ W2t,
    const float* __restrict__ bias, u16* __restrict__ out,
    int n, int ncols) {
    __shared__ __align__(16) u16 As[128 * 32];
    __shared__ __align__(16) u16 Bs[128 * 32];
    const int tid  = threadIdx.x;
    const int lane = tid & 63;
    const int w    = tid >> 6;      // wave 0..3
    const int wr   = w >> 1, wc = w & 1;
    const int brow = blockIdx.x * 128;
    const int bcol = blockIdx.y * 128;
    const int nkt  = A2 ? 16 : 8;   // 2 phases x K=256 (BK=32)

    f32x4 acc[4][4];
    #pragma unroll
    for (int m = 0; m < 4; ++m)
        #pragma unroll
        for (int q = 0; q < 4; ++q)
            acc[m][q] = (f32x4){0.f, 0.f, 0.f, 0.f};

    // staging: thread t covers rows r0 and r0+64, k-chunk ck (8 bf16 = 16B)
    const int r0 = tid >> 2;
    const int r1 = r0 + 64;
    const int ck = (tid & 3) * 8;
    int arow0 = brow + r0; if (arow0 >= n) arow0 = n - 1;
    int arow1 = brow + r1; if (arow1 >= n) arow1 = n - 1;
    const size_t a0b = (size_t)arow0 * HID + ck;
    const size_t a1b = (size_t)arow1 * HID + ck;
    const size_t b0b = (size_t)(bcol + r0) * HID + ck;   // Wt row stride = 256
    const size_t b1b = (size_t)(bcol + r1) * HID + ck;

    const int lr = lane & 15;
    const int kc = (lane >> 4) * 8;

    for (int kt = 0; kt < nkt; ++kt) {
        const u16* A = (kt < 8) ? A1 : A2;
        const u16* W = (kt < 8) ? W1t : W2t;
        const int k0 = (kt & 7) * 32;
        uint4 av0 = *(const uint4*)(A + a0b + k0);
        uint4 av1 = *(const uint4*)(A + a1b + k0);
        uint4 bv0 = *(const uint4*)(W + b0b + k0);
        uint4 bv1 = *(const uint4*)(W + b1b + k0);
        __syncthreads();                      // previous tile's reads done
        *(uint4*)&As[r0 * 32 + ck] = av0;
        *(uint4*)&As[r1 * 32 + ck] = av1;
        *(uint4*)&Bs[r0 * 32 + ck] = bv0;
        *(uint4*)&Bs[r1 * 32 + ck] = bv1;
        __syncthreads();                      // tile staged
        bf16x8 af[4], bg[4];
        #pragma unroll
        for (int m = 0; m < 4; ++m)
            af[m] = *(const bf16x8*)&As[(wr * 64 + m * 16 + lr) * 32 + kc];
        #pragma unroll
        for (int q = 0; q < 4; ++q)
            bg[q] = *(const bf16x8*)&Bs[(wc * 64 + q * 16 + lr) * 32 + kc];
        #pragma unroll
        for (int m = 0; m < 4; ++m)
            #pragma unroll
            for (int q = 0; q < 4; ++q)
                acc[m][q] = __builtin_amdgcn_mfma_f32_16x16x32_bf16(
                    af[m], bg[q], acc[m][q], 0, 0, 0);
    }

    // epilogue: C/D layout col=lane&15, row=(lane>>4)*4+j  [m89-verified]
    const int lq = lane >> 4;
    #pragma unroll
    for (int q = 0; q < 4; ++q) {
        int col = bcol + wc * 64 + q * 16 + lr;
        float bb = bias[col];
        #pragma unroll
        for (int m = 0; m < 4; ++m) {
            #pragma unroll
            for (int j = 0; j < 4; ++j) {
                int row = brow + wr * 64 + m * 16 + lq * 4 + j;
                if (row < n) {
                    float v = acc[m][q][j] + bb;
                    out[(size_t)row * ncols + col] = f2bf(fmaxf(v, 0.f));
                }
            }
        }
    }
}

// ---------------- attention scores: s = h @ att_w + att_b (h bf16) ----------------
__global__ void k_score(const u16* __restrict__ h, const float* __restrict__ att_w,
                        const float* __restrict__ att_b, float* __restrict__ s, int n) {
    int gw = (blockIdx.x * blockDim.x + threadIdx.x) >> 6;
    int lane = threadIdx.x & 63;
    if (gw >= n) return;
    uint2 v = *(const uint2*)&h[(size_t)gw * HID + lane * 4];
    float4 wv = *(const float4*)&att_w[lane * 4];
    float p = bf2f(v.x) * wv.x + bf2f(v.x >> 16) * wv.y
            + bf2f(v.y) * wv.z + bf2f(v.y >> 16) * wv.w;
    #pragma unroll
    for (int off = 32; off; off >>= 1) p += __shfl_xor(p, off, 64);
    if (lane == 0) s[gw] = p + att_b[0];
}

// ---------------- graph start offsets from sorted batch ----------------
__global__ void k_gstart(const int* __restrict__ batch, int* __restrict__ gstart, int n, int G) {
    int i = blockIdx.x * blockDim.x + threadIdx.x;
    if (i >= n) return;
    int b = batch[i];
    int bp = (i == 0) ? -1 : batch[i - 1];
    for (int g = bp + 1; g <= b; ++g) gstart[g] = i;
    if (i == n - 1) {
        for (int g = b + 1; g <= G; ++g) gstart[g] = n;
    }
}

// ---------------- per-graph max + softmax denom ----------------
__global__ void k_mdenom(const float* __restrict__ s, const int* __restrict__ gstart,
                         float* __restrict__ m, float* __restrict__ denom) {
    int g = blockIdx.x;
    int t = threadIdx.x;
    int i0 = gstart[g], i1 = gstart[g + 1];
    __shared__ float red[256];
    float mx = -INFINITY;
    for (int i = i0 + t; i < i1; i += 256) mx = fmaxf(mx, s[i]);
    red[t] = mx; __syncthreads();
    for (int st = 128; st; st >>= 1) {
        if (t < st) red[t] = fmaxf(red[t], red[t + st]);
        __syncthreads();
    }
    float gm = red[0];
    __syncthreads();
    float sm = 0.f;
    for (int i = i0 + t; i < i1; i += 256) sm += expf(s[i] - gm);
    red[t] = sm; __syncthreads();
    for (int st = 128; st; st >>= 1) {
        if (t < st) red[t] += red[t + st];
        __syncthreads();
    }
    if (t == 0) { m[g] = gm; denom[g] = red[0]; }
}

__global__ void k_alpha(const float* __restrict__ s, const int* __restrict__ batch,
                        const float* __restrict__ m, const float* __restrict__ denom,
                        float* __restrict__ alpha, int n) {
    int i = blockIdx.x * blockDim.x + threadIdx.x;
    if (i >= n) return;
    int b = batch[i];
    float d = denom[b];
    alpha[i] = (d > 0.f) ? expf(s[i] - m[b]) / d : 0.f;
}

// ---------------- attention pooling: gpool[g] = sum alpha_i * h_i (h bf16) ----------------
__global__ void k_pool(const u16* __restrict__ h, const float* __restrict__ alpha,
                       const int* __restrict__ gstart, float* __restrict__ gpool) {
    int g = blockIdx.x, sp = blockIdx.y, t = threadIdx.x;
    int i0 = gstart[g], i1 = gstart[g + 1];
    int len = i1 - i0;
    int a = i0 + (int)((long long)len * sp / 16);
    int b = i0 + (int)((long long)len * (sp + 1) / 16);
    float acc = 0.f;
    for (int i = a; i < b; ++i) acc += alpha[i] * bf2f(h[(size_t)i * HID + t]);
    if (acc != 0.f || sp == 0) atomicAdd(&gpool[g * HID + t], acc);
}

// ---------------- graph head: out[g] = relu(gpool@W1+b1)@W2 + b2 (fp32) ----------------
__global__ void k_ghead(const float* __restrict__ gpool, const float* __restrict__ W1,
                        const float* __restrict__ b1, const float* __restrict__ W2,
                        const float* __restrict__ b2, float* __restrict__ out) {
    int g = blockIdx.x, t = threadIdx.x;  // 128 threads
    __shared__ float row[HID];
    __shared__ float red[128];
    row[t] = gpool[g * HID + t];
    row[t + 128] = gpool[g * HID + t + 128];
    __syncthreads();
    float acc = 0.f;
    #pragma unroll 8
    for (int k = 0; k < HID; ++k) acc = fmaf(row[k], W1[k * HHALF + t], acc);
    float hid = fmaxf(acc + b1[t], 0.f);
    red[t] = hid * W2[t];
    __syncthreads();
    for (int st = 64; st; st >>= 1) {
        if (t < st) red[t] += red[t + st];
        __syncthreads();
    }
    if (t == 0) out[g] = red[0] + b2[0];
}

// ---------------- node head second layer: out[i] = hid[i]@W2 + b2 (hid bf16) ----------------
__global__ void k_ndot(const u16* __restrict__ hid, const float* __restrict__ W2,
                       const float* __restrict__ b2, float* __restrict__ out, int n) {
    int gw = (blockIdx.x * blockDim.x + threadIdx.x) >> 6;
    int lane = threadIdx.x & 63;
    if (gw >= n) return;
    unsigned v = *(const unsigned*)&hid[(size_t)gw * HHALF + lane * 2];
    float val = bf2f(v) * W2[lane * 2] + bf2f(v >> 16) * W2[lane * 2 + 1];
    #pragma unroll
    for (int off = 32; off; off >>= 1) val += __shfl_xor(val, off, 64);
    if (lane == 0) out[gw] = val + b2[0];
}

extern "C" void kernel_launch(void* const* d_in, const int* in_sizes, int n_in,
                              void* d_out, int out_size, void* d_ws, size_t ws_size,
                              hipStream_t stream) {
    const float* x      = (const float*)d_in[0];
    const int*   eidx   = (const int*)d_in[1];
    const int*   batch  = (const int*)d_in[2];
    const float* Ws     = (const float*)d_in[3];
    const float* Wn     = (const float*)d_in[4];
    const float* bs     = (const float*)d_in[5];
    const float* att_w  = (const float*)d_in[6];
    const float* att_b  = (const float*)d_in[7];
    const float* ne_W1  = (const float*)d_in[8];
    const float* ne_b1  = (const float*)d_in[9];
    const float* ne_W2  = (const float*)d_in[10];
    const float* ne_b2  = (const float*)d_in[11];
    const float* nd_W1  = (const float*)d_in[12];
    const float* nd_b1  = (const float*)d_in[13];
    const float* nd_W2  = (const float*)d_in[14];
    const float* nd_b2  = (const float*)d_in[15];
    float* out = (float*)d_out;

    const int N = in_sizes[2];
    const int E = in_sizes[1] / 2;
    const int L = in_sizes[3] / (HID * HID);
    const int G = out_size - N;

    const int* src = eidx;
    const int* dst = eidx + E;

    // workspace carve-up
    size_t off = 0;
    auto alloc = [&](size_t bytes) {
        void* p = (char*)d_ws + off;
        off += (bytes + 255) & ~(size_t)255;
        return p;
    };
    int*   cnt     = (int*)alloc((size_t)N * 4);
    int*   row_off = (int*)alloc((size_t)(N + 1) * 4);
    int*   fill    = (int*)alloc((size_t)N * 4);
    int*   col     = (int*)alloc((size_t)E * 4);
    int*   gstart  = (int*)alloc((size_t)(G + 1) * 4);
    int*   bsum    = (int*)alloc(1024 * 4);
    float* sarr    = (float*)alloc((size_t)N * 4);
    float* alpha   = (float*)alloc((size_t)N * 4);
    float* marr    = (float*)alloc((size_t)G * 4);
    float* denom   = (float*)alloc((size_t)G * 4);
    float* gpool   = (float*)alloc((size_t)G * HID * 4);
    u16*   xb      = (u16*)alloc((size_t)N * HID * 2);
    u16*   msgb    = (u16*)alloc((size_t)N * HID * 2);
    u16*   hb1     = (u16*)alloc((size_t)N * HID * 2);
    u16*   hb2     = (u16*)alloc((size_t)N * HID * 2);
    u16*   hidb    = (u16*)alloc((size_t)N * HHALF * 2);
    u16*   WsT     = (u16*)alloc((size_t)L * HID * HID * 2);
    u16*   WnT     = (u16*)alloc((size_t)L * HID * HID * 2);
    u16*   ndW1T   = (u16*)alloc((size_t)HID * HHALF * 2);
    (void)ws_size;

    const int eb = (E + 255) / 256;
    const int nb = (N + 255) / 256;

    // ---- CSR build (reused across layers) ----
    hipMemsetAsync(cnt, 0, (size_t)N * 4, stream);
    k_count<<<eb, 256, 0, stream>>>(dst, cnt, E);
    k_scan_block<<<nb, 256, 0, stream>>>(cnt, bsum, N);
    k_scan_top<<<1, 512, 0, stream>>>(bsum, nb);
    k_scan_down<<<nb, 256, 0, stream>>>(cnt, bsum, row_off, N, E);
    hipMemsetAsync(fill, 0, (size_t)N * 4, stream);
    k_scatter<<<eb, 256, 0, stream>>>(src, dst, row_off, fill, col, E);

    // ---- conversions: x -> bf16; weights -> transposed bf16 ----
    k_f2b<<<(N * HID / 4 + 255) / 256, 256, 0, stream>>>(x, xb, N * HID / 4);
    for (int l = 0; l < L; ++l) {
        k_wt<<<(HID * HID + 255) / 256, 256, 0, stream>>>(
            Ws + (size_t)l * HID * HID, WsT + (size_t)l * HID * HID, HID, HID);
        k_wt<<<(HID * HID + 255) / 256, 256, 0, stream>>>(
            Wn + (size_t)l * HID * HID, WnT + (size_t)l * HID * HID, HID, HID);
    }
    k_wt<<<(HID * HHALF + 255) / 256, 256, 0, stream>>>(nd_W1, ndW1T, HID, HHALF);

    // ---- GNN layers (bf16 MFMA) ----
    const int gx = (N + 127) / 128;
    const u16* hin = xb;
    u16* hout = hb1;
    for (int l = 0; l < L; ++l) {
        k_agg<<<N, 64, 0, stream>>>(hin, row_off, col, msgb, N);
        k_gemm_bf<<<dim3(gx, HID / 128), 256, 0, stream>>>(
            hin, WsT + (size_t)l * HID * HID, msgb, WnT + (size_t)l * HID * HID,
            bs + (size_t)l * HID, hout, N, HID);
        hin = hout;
        hout = (hout == hb1) ? hb2 : hb1;
    }
    const u16* h = hin;  // final node embeddings (bf16)

    // ---- attention pooling ----
    k_score<<<(N + 3) / 4, 256, 0, stream>>>(h, att_w, att_b, sarr, N);
    k_gstart<<<nb, 256, 0, stream>>>(batch, gstart, N, G);
    k_mdenom<<<G, 256, 0, stream>>>(sarr, gstart, marr, denom);
    k_alpha<<<nb, 256, 0, stream>>>(sarr, batch, marr, denom, alpha, N);
    hipMemsetAsync(gpool, 0, (size_t)G * HID * 4, stream);
    k_pool<<<dim3(G, 16), HID, 0, stream>>>(h, alpha, gstart, gpool);

    // ---- graph head ----
    k_ghead<<<G, HHALF, 0, stream>>>(gpool, ne_W1, ne_b1, ne_W2, ne_b2, out);

    // ---- node head ----
    k_gemm_bf<<<dim3(gx, 1), 256, 0, stream>>>(
        h, ndW1T, nullptr, nullptr, nd_b1, hidb, N, HHALF);
    k_ndot<<<(N + 3) / 4, 256, 0, stream>>>(hidb, nd_W2, nd_b2, out + G, N);
}

// Round 4
// 613.917 us; speedup vs baseline: 3.1001x; 1.1193x over previous
//
#include <hip/hip_runtime.h>
#include <hip/hip_bf16.h>

#define HID 256
#define HHALF 128
#define LSTR 40   // LDS row stride in u16: 80B -> max 2-way bank conflict (free), 16B-aligned

typedef unsigned short u16;
typedef __attribute__((ext_vector_type(8))) short bf16x8;
typedef __attribute__((ext_vector_type(4))) float f32x4;

__device__ __forceinline__ float bf2f(unsigned int u) {
    unsigned int x = (u & 0xffffu) << 16;
    union { unsigned int i; float f; } c; c.i = x; return c.f;
}
__device__ __forceinline__ u16 f2bf(float f) {
    __hip_bfloat16 h = __float2bfloat16(f);   // RNE
    union { __hip_bfloat16 h; u16 u; } c; c.h = h; return c.u;
}

// ---------------- CSR build ----------------
__global__ void k_count(const int* __restrict__ dst, int* __restrict__ cnt, int E) {
    int i = blockIdx.x * blockDim.x + threadIdx.x;
    if (i < E) atomicAdd(&cnt[dst[i]], 1);
}

__global__ void k_scan_block(const int* __restrict__ cnt, int* __restrict__ bsum, int n) {
    __shared__ int sd[256];
    int tid = threadIdx.x;
    int i = blockIdx.x * 256 + tid;
    int v = (i < n) ? cnt[i] : 0;
    sd[tid] = v; __syncthreads();
    for (int s = 128; s > 0; s >>= 1) {
        if (tid < s) sd[tid] += sd[tid + s];
        __syncthreads();
    }
    if (tid == 0) bsum[blockIdx.x] = sd[0];
}

__global__ void k_scan_top(int* __restrict__ bsum, int nb) {
    __shared__ int sd[512];
    int t = threadIdx.x;
    int v = (t < nb) ? bsum[t] : 0;
    sd[t] = v; __syncthreads();
    for (int s = 1; s < 512; s <<= 1) {
        int x = (t >= s) ? sd[t - s] : 0;
        __syncthreads();
        sd[t] += x;
        __syncthreads();
    }
    if (t < nb) bsum[t] = sd[t] - v;  // exclusive
}

__global__ void k_scan_down(const int* __restrict__ cnt, const int* __restrict__ boff,
                            int* __restrict__ row_off, int n, int total) {
    __shared__ int sd[256];
    int tid = threadIdx.x;
    int i = blockIdx.x * 256 + tid;
    int v = (i < n) ? cnt[i] : 0;
    sd[tid] = v; __syncthreads();
    for (int s = 1; s < 256; s <<= 1) {
        int x = (tid >= s) ? sd[tid - s] : 0;
        __syncthreads();
        sd[tid] += x;
        __syncthreads();
    }
    if (i < n) row_off[i] = boff[blockIdx.x] + sd[tid] - v;
    if (i == 0) row_off[n] = total;
}

__global__ void k_scatter(const int* __restrict__ src, const int* __restrict__ dst,
                          const int* __restrict__ row_off, int* __restrict__ fill,
                          int* __restrict__ col, int E) {
    int i = blockIdx.x * blockDim.x + threadIdx.x;
    if (i < E) {
        int d = dst[i];
        int p = atomicAdd(&fill[d], 1);
        col[row_off[d] + p] = src[i];
    }
}

// ---------------- conversions ----------------
__global__ void k_f2b(const float* __restrict__ in, u16* __restrict__ o, int total4) {
    int i = blockIdx.x * blockDim.x + threadIdx.x;
    if (i >= total4) return;
    float4 v = *(const float4*)&in[(size_t)i * 4];
    uint2 p;
    p.x = (unsigned)f2bf(v.x) | ((unsigned)f2bf(v.y) << 16);
    p.y = (unsigned)f2bf(v.z) | ((unsigned)f2bf(v.w) << 16);
    *(uint2*)&o[(size_t)i * 4] = p;
}

// W [K][C] fp32 -> Wt [C][K] bf16
__global__ void k_wt(const float* __restrict__ W, u16* __restrict__ Wt, int K, int C) {
    int idx = blockIdx.x * blockDim.x + threadIdx.x;
    if (idx >= K * C) return;
    int k = idx / C, c = idx - k * C;
    Wt[c * K + k] = f2bf(W[idx]);
}

// ---------------- mean aggregation (bf16 in/out, fp32 accum) ----------------
// 4 waves/block, one node per wave; neighbor loop unrolled x4 for MLP
__global__ __launch_bounds__(256) void k_agg(
    const u16* __restrict__ h, const int* __restrict__ row_off,
    const int* __restrict__ col, u16* __restrict__ msg, int n) {
    int node = blockIdx.x * 4 + (threadIdx.x >> 6);
    if (node >= n) return;
    int t = threadIdx.x & 63;
    int s0 = row_off[node], s1 = row_off[node + 1];
    float a0 = 0.f, a1 = 0.f, a2 = 0.f, a3 = 0.f;
    int e = s0;
    for (; e + 4 <= s1; e += 4) {
        int c0 = col[e], c1 = col[e + 1], c2 = col[e + 2], c3 = col[e + 3];
        uint2 v0 = *(const uint2*)&h[(size_t)c0 * HID + t * 4];
        uint2 v1 = *(const uint2*)&h[(size_t)c1 * HID + t * 4];
        uint2 v2 = *(const uint2*)&h[(size_t)c2 * HID + t * 4];
        uint2 v3 = *(const uint2*)&h[(size_t)c3 * HID + t * 4];
        a0 += bf2f(v0.x) + bf2f(v1.x) + bf2f(v2.x) + bf2f(v3.x);
        a1 += bf2f(v0.x >> 16) + bf2f(v1.x >> 16) + bf2f(v2.x >> 16) + bf2f(v3.x >> 16);
        a2 += bf2f(v0.y) + bf2f(v1.y) + bf2f(v2.y) + bf2f(v3.y);
        a3 += bf2f(v0.y >> 16) + bf2f(v1.y >> 16) + bf2f(v2.y >> 16) + bf2f(v3.y >> 16);
    }
    for (; e < s1; ++e) {
        int c = col[e];
        uint2 v = *(const uint2*)&h[(size_t)c * HID + t * 4];
        a0 += bf2f(v.x); a1 += bf2f(v.x >> 16);
        a2 += bf2f(v.y); a3 += bf2f(v.y >> 16);
    }
    int deg = s1 - s0;
    float inv = 1.0f / (float)(deg > 1 ? deg : 1);
    uint2 o;
    o.x = (unsigned)f2bf(a0 * inv) | ((unsigned)f2bf(a1 * inv) << 16);
    o.y = (unsigned)f2bf(a2 * inv) | ((unsigned)f2bf(a3 * inv) << 16);
    *(uint2*)&msg[(size_t)node * HID + t * 4] = o;
}

// ---------------- bf16 MFMA GEMM: out = relu(A1@W1 [+ A2@W2] + bias) ----------------
// 128x256 tile, 8 waves (2x4), BK=32. Wt pre-transposed [256][256].
// MFMA operands SWAPPED (bg first) so each lane holds 4 consecutive output
// cols of one row -> packed 8B stores (kills the 2x write amplification).
__global__ __launch_bounds__(512) void k_gemm_bf(
    const u16* __restrict__ A1, const u16* __restrict__ W1t,
    const u16* __restrict__ A2, const u16* __restrict__ W2t,
    const float* __restrict__ bias, u16* __restrict__ out,
    int n, int ncols) {
    __shared__ __align__(16) u16 As[128 * LSTR];
    __shared__ __align__(16) u16 Bs[256 * LSTR];
    const int tid  = threadIdx.x;
    const int lane = tid & 63;
    const int w    = tid >> 6;          // 0..7
    const int wr   = w >> 2, wc = w & 3; // wave tile: rows wr*64+, cols wc*64+
    const int brow = blockIdx.x * 128;
    const int nkt  = A2 ? 16 : 8;

    f32x4 acc[4][4];
    #pragma unroll
    for (int m = 0; m < 4; ++m)
        #pragma unroll
        for (int q = 0; q < 4; ++q)
            acc[m][q] = (f32x4){0.f, 0.f, 0.f, 0.f};

    // staging: 16B chunks. As: 512 chunks (1/thread). Bs: 1024 chunks (2/thread).
    const int sr  = tid >> 2;            // 0..127
    const int sck = (tid & 3) * 8;
    int arow = brow + sr; if (arow >= n) arow = n - 1;
    const size_t abase  = (size_t)arow * HID + sck;
    const size_t b0base = (size_t)sr * HID + sck;          // Wt rows 0..127
    const size_t b1base = (size_t)(sr + 128) * HID + sck;  // Wt rows 128..255

    const int lr = lane & 15;
    const int kc = (lane >> 4) * 8;

    for (int kt = 0; kt < nkt; ++kt) {
        const u16* A = (kt < 8) ? A1 : A2;
        const u16* W = (kt < 8) ? W1t : W2t;
        const int k0 = (kt & 7) * 32;
        uint4 av  = *(const uint4*)(A + abase + k0);
        uint4 bv0 = *(const uint4*)(W + b0base + k0);
        uint4 bv1 = *(const uint4*)(W + b1base + k0);
        __syncthreads();
        *(uint4*)&As[sr * LSTR + sck] = av;
        *(uint4*)&Bs[sr * LSTR + sck] = bv0;
        *(uint4*)&Bs[(sr + 128) * LSTR + sck] = bv1;
        __syncthreads();
        bf16x8 af[4], bg[4];
        #pragma unroll
        for (int m = 0; m < 4; ++m)
            af[m] = *(const bf16x8*)&As[(wr * 64 + m * 16 + lr) * LSTR + kc];
        #pragma unroll
        for (int q = 0; q < 4; ++q)
            bg[q] = *(const bf16x8*)&Bs[(wc * 64 + q * 16 + lr) * LSTR + kc];
        #pragma unroll
        for (int m = 0; m < 4; ++m)
            #pragma unroll
            for (int q = 0; q < 4; ++q)
                acc[m][q] = __builtin_amdgcn_mfma_f32_16x16x32_bf16(
                    bg[q], af[m], acc[m][q], 0, 0, 0);  // swapped: lane holds 4 cols of a row
    }

    // epilogue: row = brow+wr*64+m*16+(lane&15); col = wc*64+q*16+(lane>>4)*4+j
    const int lq = lane >> 4;
    #pragma unroll
    for (int m = 0; m < 4; ++m) {
        int row = brow + wr * 64 + m * 16 + lr;
        if (row >= n) continue;
        #pragma unroll
        for (int q = 0; q < 4; ++q) {
            int col = wc * 64 + q * 16 + lq * 4;
            if (col < ncols) {
                float4 bb = *(const float4*)&bias[col];
                uint2 o;
                o.x = (unsigned)f2bf(fmaxf(acc[m][q][0] + bb.x, 0.f))
                    | ((unsigned)f2bf(fmaxf(acc[m][q][1] + bb.y, 0.f)) << 16);
                o.y = (unsigned)f2bf(fmaxf(acc[m][q][2] + bb.z, 0.f))
                    | ((unsigned)f2bf(fmaxf(acc[m][q][3] + bb.w, 0.f)) << 16);
                *(uint2*)&out[(size_t)row * ncols + col] = o;
            }
        }
    }
}

// ---------------- attention scores: s = h @ att_w + att_b (h bf16) ----------------
__global__ void k_score(const u16* __restrict__ h, const float* __restrict__ att_w,
                        const float* __restrict__ att_b, float* __restrict__ s, int n) {
    int gw = (blockIdx.x * blockDim.x + threadIdx.x) >> 6;
    int lane = threadIdx.x & 63;
    if (gw >= n) return;
    uint2 v = *(const uint2*)&h[(size_t)gw * HID + lane * 4];
    float4 wv = *(const float4*)&att_w[lane * 4];
    float p = bf2f(v.x) * wv.x + bf2f(v.x >> 16) * wv.y
            + bf2f(v.y) * wv.z + bf2f(v.y >> 16) * wv.w;
    #pragma unroll
    for (int off = 32; off; off >>= 1) p += __shfl_xor(p, off, 64);
    if (lane == 0) s[gw] = p + att_b[0];
}

// ---------------- graph start offsets from sorted batch ----------------
__global__ void k_gstart(const int* __restrict__ batch, int* __restrict__ gstart, int n, int G) {
    int i = blockIdx.x * blockDim.x + threadIdx.x;
    if (i >= n) return;
    int b = batch[i];
    int bp = (i == 0) ? -1 : batch[i - 1];
    for (int g = bp + 1; g <= b; ++g) gstart[g] = i;
    if (i == n - 1) {
        for (int g = b + 1; g <= G; ++g) gstart[g] = n;
    }
}

// ---------------- per-graph max + softmax denom ----------------
__global__ void k_mdenom(const float* __restrict__ s, const int* __restrict__ gstart,
                         float* __restrict__ m, float* __restrict__ denom) {
    int g = blockIdx.x;
    int t = threadIdx.x;
    int i0 = gstart[g], i1 = gstart[g + 1];
    __shared__ float red[256];
    float mx = -INFINITY;
    for (int i = i0 + t; i < i1; i += 256) mx = fmaxf(mx, s[i]);
    red[t] = mx; __syncthreads();
    for (int st = 128; st; st >>= 1) {
        if (t < st) red[t] = fmaxf(red[t], red[t + st]);
        __syncthreads();
    }
    float gm = red[0];
    __syncthreads();
    float sm = 0.f;
    for (int i = i0 + t; i < i1; i += 256) sm += expf(s[i] - gm);
    red[t] = sm; __syncthreads();
    for (int st = 128; st; st >>= 1) {
        if (t < st) red[t] += red[t + st];
        __syncthreads();
    }
    if (t == 0) { m[g] = gm; denom[g] = red[0]; }
}

__global__ void k_alpha(const float* __restrict__ s, const int* __restrict__ batch,
                        const float* __restrict__ m, const float* __restrict__ denom,
                        float* __restrict__ alpha, int n) {
    int i = blockIdx.x * blockDim.x + threadIdx.x;
    if (i >= n) return;
    int b = batch[i];
    float d = denom[b];
    alpha[i] = (d > 0.f) ? expf(s[i] - m[b]) / d : 0.f;
}

// ---------------- attention pooling: gpool[g] = sum alpha_i * h_i (h bf16) ----------------
__global__ void k_pool(const u16* __restrict__ h, const float* __restrict__ alpha,
                       const int* __restrict__ gstart, float* __restrict__ gpool) {
    int g = blockIdx.x, sp = blockIdx.y, t = threadIdx.x;
    int i0 = gstart[g], i1 = gstart[g + 1];
    int len = i1 - i0;
    int a = i0 + (int)((long long)len * sp / 16);
    int b = i0 + (int)((long long)len * (sp + 1) / 16);
    float acc = 0.f;
    for (int i = a; i < b; ++i) acc += alpha[i] * bf2f(h[(size_t)i * HID + t]);
    if (acc != 0.f || sp == 0) atomicAdd(&gpool[g * HID + t], acc);
}

// ---------------- graph head ----------------
__global__ void k_ghead(const float* __restrict__ gpool, const float* __restrict__ W1,
                        const float* __restrict__ b1, const float* __restrict__ W2,
                        const float* __restrict__ b2, float* __restrict__ out) {
    int g = blockIdx.x, t = threadIdx.x;  // 128 threads
    __shared__ float row[HID];
    __shared__ float red[128];
    row[t] = gpool[g * HID + t];
    row[t + 128] = gpool[g * HID + t + 128];
    __syncthreads();
    float acc = 0.f;
    #pragma unroll 8
    for (int k = 0; k < HID; ++k) acc = fmaf(row[k], W1[k * HHALF + t], acc);
    float hid = fmaxf(acc + b1[t], 0.f);
    red[t] = hid * W2[t];
    __syncthreads();
    for (int st = 64; st; st >>= 1) {
        if (t < st) red[t] += red[t + st];
        __syncthreads();
    }
    if (t == 0) out[g] = red[0] + b2[0];
}

// ---------------- node head second layer ----------------
__global__ void k_ndot(const u16* __restrict__ hid, const float* __restrict__ W2,
                       const float* __restrict__ b2, float* __restrict__ out, int n) {
    int gw = (blockIdx.x * blockDim.x + threadIdx.x) >> 6;
    int lane = threadIdx.x & 63;
    if (gw >= n) return;
    unsigned v = *(const unsigned*)&hid[(size_t)gw * HHALF + lane * 2];
    float val = bf2f(v) * W2[lane * 2] + bf2f(v >> 16) * W2[lane * 2 + 1];
    #pragma unroll
    for (int off = 32; off; off >>= 1) val += __shfl_xor(val, off, 64);
    if (lane == 0) out[gw] = val + b2[0];
}

extern "C" void kernel_launch(void* const* d_in, const int* in_sizes, int n_in,
                              void* d_out, int out_size, void* d_ws, size_t ws_size,
                              hipStream_t stream) {
    const float* x      = (const float*)d_in[0];
    const int*   eidx   = (const int*)d_in[1];
    const int*   batch  = (const int*)d_in[2];
    const float* Ws     = (const float*)d_in[3];
    const float* Wn     = (const float*)d_in[4];
    const float* bs     = (const float*)d_in[5];
    const float* att_w  = (const float*)d_in[6];
    const float* att_b  = (const float*)d_in[7];
    const float* ne_W1  = (const float*)d_in[8];
    const float* ne_b1  = (const float*)d_in[9];
    const float* ne_W2  = (const float*)d_in[10];
    const float* ne_b2  = (const float*)d_in[11];
    const float* nd_W1  = (const float*)d_in[12];
    const float* nd_b1  = (const float*)d_in[13];
    const float* nd_W2  = (const float*)d_in[14];
    const float* nd_b2  = (const float*)d_in[15];
    float* out = (float*)d_out;

    const int N = in_sizes[2];
    const int E = in_sizes[1] / 2;
    const int L = in_sizes[3] / (HID * HID);
    const int G = out_size - N;

    const int* src = eidx;
    const int* dst = eidx + E;

    size_t off = 0;
    auto alloc = [&](size_t bytes) {
        void* p = (char*)d_ws + off;
        off += (bytes + 255) & ~(size_t)255;
        return p;
    };
    int*   cnt     = (int*)alloc((size_t)N * 4);
    int*   row_off = (int*)alloc((size_t)(N + 1) * 4);
    int*   fill    = (int*)alloc((size_t)N * 4);
    int*   col     = (int*)alloc((size_t)E * 4);
    int*   gstart  = (int*)alloc((size_t)(G + 1) * 4);
    int*   bsum    = (int*)alloc(1024 * 4);
    float* sarr    = (float*)alloc((size_t)N * 4);
    float* alpha   = (float*)alloc((size_t)N * 4);
    float* marr    = (float*)alloc((size_t)G * 4);
    float* denom   = (float*)alloc((size_t)G * 4);
    float* gpool   = (float*)alloc((size_t)G * HID * 4);
    u16*   xb      = (u16*)alloc((size_t)N * HID * 2);
    u16*   msgb    = (u16*)alloc((size_t)N * HID * 2);
    u16*   hb1     = (u16*)alloc((size_t)N * HID * 2);
    u16*   hb2     = (u16*)alloc((size_t)N * HID * 2);
    u16*   hidb    = (u16*)alloc((size_t)N * HHALF * 2);
    u16*   WsT     = (u16*)alloc((size_t)L * HID * HID * 2);
    u16*   WnT     = (u16*)alloc((size_t)L * HID * HID * 2);
    u16*   ndW1T   = (u16*)alloc((size_t)HID * HID * 2);  // padded: only first 128 rows valid
    (void)ws_size;

    const int eb = (E + 255) / 256;
    const int nb = (N + 255) / 256;

    // ---- CSR build ----
    hipMemsetAsync(cnt, 0, (size_t)N * 4, stream);
    k_count<<<eb, 256, 0, stream>>>(dst, cnt, E);
    k_scan_block<<<nb, 256, 0, stream>>>(cnt, bsum, N);
    k_scan_top<<<1, 512, 0, stream>>>(bsum, nb);
    k_scan_down<<<nb, 256, 0, stream>>>(cnt, bsum, row_off, N, E);
    hipMemsetAsync(fill, 0, (size_t)N * 4, stream);
    k_scatter<<<eb, 256, 0, stream>>>(src, dst, row_off, fill, col, E);

    // ---- conversions ----
    k_f2b<<<(N * HID / 4 + 255) / 256, 256, 0, stream>>>(x, xb, N * HID / 4);
    for (int l = 0; l < L; ++l) {
        k_wt<<<(HID * HID + 255) / 256, 256, 0, stream>>>(
            Ws + (size_t)l * HID * HID, WsT + (size_t)l * HID * HID, HID, HID);
        k_wt<<<(HID * HID + 255) / 256, 256, 0, stream>>>(
            Wn + (size_t)l * HID * HID, WnT + (size_t)l * HID * HID, HID, HID);
    }
    k_wt<<<(HID * HHALF + 255) / 256, 256, 0, stream>>>(nd_W1, ndW1T, HID, HHALF);

    // ---- GNN layers ----
    const int gx = (N + 127) / 128;
    const u16* hin = xb;
    u16* hout = hb1;
    for (int l = 0; l < L; ++l) {
        k_agg<<<(N + 3) / 4, 256, 0, stream>>>(hin, row_off, col, msgb, N);
        k_gemm_bf<<<gx, 512, 0, stream>>>(
            hin, WsT + (size_t)l * HID * HID, msgb, WnT + (size_t)l * HID * HID,
            bs + (size_t)l * HID, hout, N, HID);
        hin = hout;
        hout = (hout == hb1) ? hb2 : hb1;
    }
    const u16* h = hin;

    // ---- attention pooling ----
    k_score<<<(N + 3) / 4, 256, 0, stream>>>(h, att_w, att_b, sarr, N);
    k_gstart<<<nb, 256, 0, stream>>>(batch, gstart, N, G);
    k_mdenom<<<G, 256, 0, stream>>>(sarr, gstart, marr, denom);
    k_alpha<<<nb, 256, 0, stream>>>(sarr, batch, marr, denom, alpha, N);
    hipMemsetAsync(gpool, 0, (size_t)G * HID * 4, stream);
    k_pool<<<dim3(G, 16), HID, 0, stream>>>(h, alpha, gstart, gpool);

    // ---- graph head ----
    k_ghead<<<G, HHALF, 0, stream>>>(gpool, ne_W1, ne_b1, ne_W2, ne_b2, out);

    // ---- node head ----
    k_gemm_bf<<<gx, 512, 0, stream>>>(
        h, ndW1T, nullptr, nullptr, nd_b1, hidb, N, HHALF);
    k_ndot<<<(N + 3) / 4, 256, 0, stream>>>(hidb, nd_W2, nd_b2, out + G, N);
}

// Round 5
// 586.361 us; speedup vs baseline: 3.2458x; 1.0470x over previous
//
#include <hip/hip_runtime.h>
#include <hip/hip_bf16.h>

#define HID 256
#define HHALF 128

typedef unsigned short u16;
typedef __attribute__((ext_vector_type(8))) short bf16x8;
typedef __attribute__((ext_vector_type(4))) float f32x4;

__device__ __forceinline__ float bf2f(unsigned int u) {
    unsigned int x = (u & 0xffffu) << 16;
    union { unsigned int i; float f; } c; c.i = x; return c.f;
}
__device__ __forceinline__ float lof(unsigned u) {
    union { unsigned i; float f; } c; c.i = u << 16; return c.f;
}
__device__ __forceinline__ float hif(unsigned u) {
    union { unsigned i; float f; } c; c.i = u & 0xffff0000u; return c.f;
}
__device__ __forceinline__ u16 f2bf(float f) {
    __hip_bfloat16 h = __float2bfloat16(f);   // RNE
    union { __hip_bfloat16 h; u16 u; } c; c.h = h; return c.u;
}

// async global->LDS, 16B per lane; lds ptr must be wave-uniform (dest = base + lane*16)
__device__ __forceinline__ void gload16(const u16* g, u16* l) {
    __builtin_amdgcn_global_load_lds(
        (const __attribute__((address_space(1))) void*)g,
        (__attribute__((address_space(3))) void*)l, 16, 0, 0);
}

// ---------------- CSR build ----------------
__global__ void k_count(const int* __restrict__ dst, int* __restrict__ cnt, int E) {
    int i = blockIdx.x * blockDim.x + threadIdx.x;
    if (i < E) atomicAdd(&cnt[dst[i]], 1);
}

__global__ void k_scan_block(const int* __restrict__ cnt, int* __restrict__ bsum, int n) {
    __shared__ int sd[256];
    int tid = threadIdx.x;
    int i = blockIdx.x * 256 + tid;
    int v = (i < n) ? cnt[i] : 0;
    sd[tid] = v; __syncthreads();
    for (int s = 128; s > 0; s >>= 1) {
        if (tid < s) sd[tid] += sd[tid + s];
        __syncthreads();
    }
    if (tid == 0) bsum[blockIdx.x] = sd[0];
}

__global__ void k_scan_top(int* __restrict__ bsum, int nb) {
    __shared__ int sd[512];
    int t = threadIdx.x;
    int v = (t < nb) ? bsum[t] : 0;
    sd[t] = v; __syncthreads();
    for (int s = 1; s < 512; s <<= 1) {
        int x = (t >= s) ? sd[t - s] : 0;
        __syncthreads();
        sd[t] += x;
        __syncthreads();
    }
    if (t < nb) bsum[t] = sd[t] - v;  // exclusive
}

__global__ void k_scan_down(const int* __restrict__ cnt, const int* __restrict__ boff,
                            int* __restrict__ row_off, int n, int total) {
    __shared__ int sd[256];
    int tid = threadIdx.x;
    int i = blockIdx.x * 256 + tid;
    int v = (i < n) ? cnt[i] : 0;
    sd[tid] = v; __syncthreads();
    for (int s = 1; s < 256; s <<= 1) {
        int x = (tid >= s) ? sd[tid - s] : 0;
        __syncthreads();
        sd[tid] += x;
        __syncthreads();
    }
    if (i < n) row_off[i] = boff[blockIdx.x] + sd[tid] - v;
    if (i == 0) row_off[n] = total;
}

__global__ void k_scatter(const int* __restrict__ src, const int* __restrict__ dst,
                          const int* __restrict__ row_off, int* __restrict__ fill,
                          int* __restrict__ col, int E) {
    int i = blockIdx.x * blockDim.x + threadIdx.x;
    if (i < E) {
        int d = dst[i];
        int p = atomicAdd(&fill[d], 1);
        col[row_off[d] + p] = src[i];
    }
}

// ---------------- conversions ----------------
__global__ void k_f2b(const float* __restrict__ in, u16* __restrict__ o, int total4) {
    int i = blockIdx.x * blockDim.x + threadIdx.x;
    if (i >= total4) return;
    float4 v = *(const float4*)&in[(size_t)i * 4];
    uint2 p;
    p.x = (unsigned)f2bf(v.x) | ((unsigned)f2bf(v.y) << 16);
    p.y = (unsigned)f2bf(v.z) | ((unsigned)f2bf(v.w) << 16);
    *(uint2*)&o[(size_t)i * 4] = p;
}

// all weight transposes in one launch: mats 0..L-1 = Ws, L..2L-1 = Wn, 2L = nd_W1
__global__ void k_wt_all(const float* __restrict__ Ws, const float* __restrict__ Wn,
                         const float* __restrict__ ndW1,
                         u16* __restrict__ WsT, u16* __restrict__ WnT,
                         u16* __restrict__ ndW1T, int L) {
    int idx = blockIdx.x * 256 + threadIdx.x;
    int mat = idx >> 16;            // 65536 elems per 256x256 slot
    int r = idx & 65535;
    int k = r >> 8, c = r & 255;
    if (mat < L) {
        WsT[(size_t)mat * 65536 + c * 256 + k] = f2bf(Ws[(size_t)mat * 65536 + k * 256 + c]);
    } else if (mat < 2 * L) {
        int l = mat - L;
        WnT[(size_t)l * 65536 + c * 256 + k] = f2bf(Wn[(size_t)l * 65536 + k * 256 + c]);
    } else {
        if (c < HHALF) ndW1T[c * 256 + k] = f2bf(ndW1[k * HHALF + c]);
    }
}

// ---------------- mean aggregation (bf16 in/out, fp32 accum) ----------------
// 4 waves/block, one node per wave; halves of the wave take alternate neighbors,
// each lane loads uint4 (8 channels); cross-half combine via shfl_xor(32).
__global__ __launch_bounds__(256) void k_agg(
    const u16* __restrict__ h, const int* __restrict__ row_off,
    const int* __restrict__ col, u16* __restrict__ msg, int n) {
    int node = blockIdx.x * 4 + (threadIdx.x >> 6);
    if (node >= n) return;
    int lane = threadIdx.x & 63;
    int half = lane >> 5;
    int t = lane & 31;              // owns channels t*8 .. t*8+7
    int s0 = row_off[node], s1 = row_off[node + 1];
    float a0 = 0.f, a1 = 0.f, a2 = 0.f, a3 = 0.f;
    float a4 = 0.f, a5 = 0.f, a6 = 0.f, a7 = 0.f;
    int e = s0;
    for (; e + 4 <= s1; e += 4) {
        int c0 = col[e + half];
        int c1 = col[e + 2 + half];
        uint4 v0 = *(const uint4*)&h[(size_t)c0 * HID + t * 8];
        uint4 v1 = *(const uint4*)&h[(size_t)c1 * HID + t * 8];
        a0 += lof(v0.x) + lof(v1.x); a1 += hif(v0.x) + hif(v1.x);
        a2 += lof(v0.y) + lof(v1.y); a3 += hif(v0.y) + hif(v1.y);
        a4 += lof(v0.z) + lof(v1.z); a5 += hif(v0.z) + hif(v1.z);
        a6 += lof(v0.w) + lof(v1.w); a7 += hif(v0.w) + hif(v1.w);
    }
    for (; e < s1; e += 2) {
        if (e + half < s1) {
            int c = col[e + half];
            uint4 v = *(const uint4*)&h[(size_t)c * HID + t * 8];
            a0 += lof(v.x); a1 += hif(v.x);
            a2 += lof(v.y); a3 += hif(v.y);
            a4 += lof(v.z); a5 += hif(v.z);
            a6 += lof(v.w); a7 += hif(v.w);
        }
    }
    a0 += __shfl_xor(a0, 32); a1 += __shfl_xor(a1, 32);
    a2 += __shfl_xor(a2, 32); a3 += __shfl_xor(a3, 32);
    a4 += __shfl_xor(a4, 32); a5 += __shfl_xor(a5, 32);
    a6 += __shfl_xor(a6, 32); a7 += __shfl_xor(a7, 32);
    if (half == 0) {
        int deg = s1 - s0;
        float inv = 1.0f / (float)(deg > 1 ? deg : 1);
        uint4 o;
        o.x = (unsigned)f2bf(a0 * inv) | ((unsigned)f2bf(a1 * inv) << 16);
        o.y = (unsigned)f2bf(a2 * inv) | ((unsigned)f2bf(a3 * inv) << 16);
        o.z = (unsigned)f2bf(a4 * inv) | ((unsigned)f2bf(a5 * inv) << 16);
        o.w = (unsigned)f2bf(a6 * inv) | ((unsigned)f2bf(a7 * inv) << 16);
        *(uint4*)&msg[(size_t)node * HID + t * 8] = o;
    }
}

// ---------------- bf16 MFMA GEMM: out = relu(A1@W1 [+ A2@W2] + bias) ----------------
// 128x256 tile, 8 waves (2x4), BK=32, global_load_lds staging (linear LDS) with
// XOR chunk swizzle (slot ^= (row>>1)&3) applied on BOTH global-source and read side.
__global__ __launch_bounds__(512) void k_gemm_bf(
    const u16* __restrict__ A1, const u16* __restrict__ W1t,
    const u16* __restrict__ A2, const u16* __restrict__ W2t,
    const float* __restrict__ bias, u16* __restrict__ out,
    int n, int ncols) {
    __shared__ __align__(16) u16 As[128 * 32];
    __shared__ __align__(16) u16 Bs[256 * 32];
    const int tid  = threadIdx.x;
    const int lane = tid & 63;
    const int w    = tid >> 6;           // 0..7
    const int wr   = w >> 2, wc = w & 3; // wave tile: rows wr*64+, cols wc*64+
    const int brow = blockIdx.x * 128;
    const int nkt  = A2 ? 16 : 8;

    f32x4 acc[4][4];
    #pragma unroll
    for (int m = 0; m < 4; ++m)
        #pragma unroll
        for (int q = 0; q < 4; ++q)
            acc[m][q] = (f32x4){0.f, 0.f, 0.f, 0.f};

    // staging addresses (per K-step, + k0)
    const int arow_t = w * 16 + (lane >> 2);         // A tile row this lane fetches
    int arow = brow + arow_t; if (arow >= n) arow = n - 1;
    const int ach = (lane & 3) ^ ((arow_t >> 1) & 3);
    const size_t abase = (size_t)arow * HID + ach * 8;
    u16* As_dst = &As[(w * 16) * 32];                // wave-uniform

    const int brow0 = w * 32 + (lane >> 2);
    const int bch0  = (lane & 3) ^ ((brow0 >> 1) & 3);
    const size_t bbase0 = (size_t)brow0 * HID + bch0 * 8;
    u16* Bs_dst0 = &Bs[(w * 32) * 32];
    const int brow1 = brow0 + 16;
    const int bch1  = (lane & 3) ^ ((brow1 >> 1) & 3);
    const size_t bbase1 = (size_t)brow1 * HID + bch1 * 8;
    u16* Bs_dst1 = &Bs[(w * 32 + 16) * 32];

    const int lr = lane & 15;
    const int lq = lane >> 4;
    const int ph = lq ^ ((lr >> 1) & 3);  // read-side swizzled chunk (row-dependence folds to lr)

    for (int kt = 0; kt < nkt; ++kt) {
        const u16* A = (kt < 8) ? A1 : A2;
        const u16* W = (kt < 8) ? W1t : W2t;
        const int k0 = (kt & 7) * 32;
        __syncthreads();                  // all waves done reading previous tile
        gload16(A + abase + k0, As_dst);
        gload16(W + bbase0 + k0, Bs_dst0);
        gload16(W + bbase1 + k0, Bs_dst1);
        __syncthreads();                  // vmcnt(0) drain -> tile staged
        bf16x8 af[4], bg[4];
        #pragma unroll
        for (int m = 0; m < 4; ++m)
            af[m] = *(const bf16x8*)&As[(wr * 64 + m * 16 + lr) * 32 + ph * 8];
        #pragma unroll
        for (int q = 0; q < 4; ++q)
            bg[q] = *(const bf16x8*)&Bs[(wc * 64 + q * 16 + lr) * 32 + ph * 8];
        #pragma unroll
        for (int m = 0; m < 4; ++m)
            #pragma unroll
            for (int q = 0; q < 4; ++q)
                acc[m][q] = __builtin_amdgcn_mfma_f32_16x16x32_bf16(
                    bg[q], af[m], acc[m][q], 0, 0, 0);  // swapped: lane holds 4 cols of a row
    }

    // epilogue: row = brow+wr*64+m*16+(lane&15); col = wc*64+q*16+(lane>>4)*4+j
    #pragma unroll
    for (int m = 0; m < 4; ++m) {
        int row = brow + wr * 64 + m * 16 + lr;
        if (row >= n) continue;
        #pragma unroll
        for (int q = 0; q < 4; ++q) {
            int col = wc * 64 + q * 16 + lq * 4;
            if (col < ncols) {
                float4 bb = *(const float4*)&bias[col];
                uint2 o;
                o.x = (unsigned)f2bf(fmaxf(acc[m][q][0] + bb.x, 0.f))
                    | ((unsigned)f2bf(fmaxf(acc[m][q][1] + bb.y, 0.f)) << 16);
                o.y = (unsigned)f2bf(fmaxf(acc[m][q][2] + bb.z, 0.f))
                    | ((unsigned)f2bf(fmaxf(acc[m][q][3] + bb.w, 0.f)) << 16);
                *(uint2*)&out[(size_t)row * ncols + col] = o;
            }
        }
    }
}

// ---------------- attention scores: s = h @ att_w + att_b (h bf16) ----------------
__global__ void k_score(const u16* __restrict__ h, const float* __restrict__ att_w,
                        const float* __restrict__ att_b, float* __restrict__ s, int n) {
    int gw = (blockIdx.x * blockDim.x + threadIdx.x) >> 6;
    int lane = threadIdx.x & 63;
    if (gw >= n) return;
    uint2 v = *(const uint2*)&h[(size_t)gw * HID + lane * 4];
    float4 wv = *(const float4*)&att_w[lane * 4];
    float p = bf2f(v.x) * wv.x + bf2f(v.x >> 16) * wv.y
            + bf2f(v.y) * wv.z + bf2f(v.y >> 16) * wv.w;
    #pragma unroll
    for (int off = 32; off; off >>= 1) p += __shfl_xor(p, off, 64);
    if (lane == 0) s[gw] = p + att_b[0];
}

// ---------------- graph start offsets from sorted batch ----------------
__global__ void k_gstart(const int* __restrict__ batch, int* __restrict__ gstart, int n, int G) {
    int i = blockIdx.x * blockDim.x + threadIdx.x;
    if (i >= n) return;
    int b = batch[i];
    int bp = (i == 0) ? -1 : batch[i - 1];
    for (int g = bp + 1; g <= b; ++g) gstart[g] = i;
    if (i == n - 1) {
        for (int g = b + 1; g <= G; ++g) gstart[g] = n;
    }
}

// ---------------- per-graph max + softmax denom ----------------
__global__ void k_mdenom(const float* __restrict__ s, const int* __restrict__ gstart,
                         float* __restrict__ m, float* __restrict__ denom) {
    int g = blockIdx.x;
    int t = threadIdx.x;
    int i0 = gstart[g], i1 = gstart[g + 1];
    __shared__ float red[256];
    float mx = -INFINITY;
    for (int i = i0 + t; i < i1; i += 256) mx = fmaxf(mx, s[i]);
    red[t] = mx; __syncthreads();
    for (int st = 128; st; st >>= 1) {
        if (t < st) red[t] = fmaxf(red[t], red[t + st]);
        __syncthreads();
    }
    float gm = red[0];
    __syncthreads();
    float sm = 0.f;
    for (int i = i0 + t; i < i1; i += 256) sm += expf(s[i] - gm);
    red[t] = sm; __syncthreads();
    for (int st = 128; st; st >>= 1) {
        if (t < st) red[t] += red[t + st];
        __syncthreads();
    }
    if (t == 0) { m[g] = gm; denom[g] = red[0]; }
}

__global__ void k_alpha(const float* __restrict__ s, const int* __restrict__ batch,
                        const float* __restrict__ m, const float* __restrict__ denom,
                        float* __restrict__ alpha, int n) {
    int i = blockIdx.x * blockDim.x + threadIdx.x;
    if (i >= n) return;
    int b = batch[i];
    float d = denom[b];
    alpha[i] = (d > 0.f) ? expf(s[i] - m[b]) / d : 0.f;
}

// ---------------- attention pooling: gpool[g] = sum alpha_i * h_i (h bf16) ----------------
__global__ void k_pool(const u16* __restrict__ h, const float* __restrict__ alpha,
                       const int* __restrict__ gstart, float* __restrict__ gpool) {
    int g = blockIdx.x, sp = blockIdx.y, t = threadIdx.x;
    int i0 = gstart[g], i1 = gstart[g + 1];
    int len = i1 - i0;
    int a = i0 + (int)((long long)len * sp / 16);
    int b = i0 + (int)((long long)len * (sp + 1) / 16);
    float acc = 0.f;
    for (int i = a; i < b; ++i) acc += alpha[i] * bf2f(h[(size_t)i * HID + t]);
    if (acc != 0.f || sp == 0) atomicAdd(&gpool[g * HID + t], acc);
}

// ---------------- graph head ----------------
__global__ void k_ghead(const float* __restrict__ gpool, const float* __restrict__ W1,
                        const float* __restrict__ b1, const float* __restrict__ W2,
                        const float* __restrict__ b2, float* __restrict__ out) {
    int g = blockIdx.x, t = threadIdx.x;  // 128 threads
    __shared__ float row[HID];
    __shared__ float red[128];
    row[t] = gpool[g * HID + t];
    row[t + 128] = gpool[g * HID + t + 128];
    __syncthreads();
    float acc = 0.f;
    #pragma unroll 8
    for (int k = 0; k < HID; ++k) acc = fmaf(row[k], W1[k * HHALF + t], acc);
    float hid = fmaxf(acc + b1[t], 0.f);
    red[t] = hid * W2[t];
    __syncthreads();
    for (int st = 64; st; st >>= 1) {
        if (t < st) red[t] += red[t + st];
        __syncthreads();
    }
    if (t == 0) out[g] = red[0] + b2[0];
}

// ---------------- node head second layer ----------------
__global__ void k_ndot(const u16* __restrict__ hid, const float* __restrict__ W2,
                       const float* __restrict__ b2, float* __restrict__ out, int n) {
    int gw = (blockIdx.x * blockDim.x + threadIdx.x) >> 6;
    int lane = threadIdx.x & 63;
    if (gw >= n) return;
    unsigned v = *(const unsigned*)&hid[(size_t)gw * HHALF + lane * 2];
    float val = bf2f(v) * W2[lane * 2] + bf2f(v >> 16) * W2[lane * 2 + 1];
    #pragma unroll
    for (int off = 32; off; off >>= 1) val += __shfl_xor(val, off, 64);
    if (lane == 0) out[gw] = val + b2[0];
}

extern "C" void kernel_launch(void* const* d_in, const int* in_sizes, int n_in,
                              void* d_out, int out_size, void* d_ws, size_t ws_size,
                              hipStream_t stream) {
    const float* x      = (const float*)d_in[0];
    const int*   eidx   = (const int*)d_in[1];
    const int*   batch  = (const int*)d_in[2];
    const float* Ws     = (const float*)d_in[3];
    const float* Wn     = (const float*)d_in[4];
    const float* bs     = (const float*)d_in[5];
    const float* att_w  = (const float*)d_in[6];
    const float* att_b  = (const float*)d_in[7];
    const float* ne_W1  = (const float*)d_in[8];
    const float* ne_b1  = (const float*)d_in[9];
    const float* ne_W2  = (const float*)d_in[10];
    const float* ne_b2  = (const float*)d_in[11];
    const float* nd_W1  = (const float*)d_in[12];
    const float* nd_b1  = (const float*)d_in[13];
    const float* nd_W2  = (const float*)d_in[14];
    const float* nd_b2  = (const float*)d_in[15];
    float* out = (float*)d_out;

    const int N = in_sizes[2];
    const int E = in_sizes[1] / 2;
    const int L = in_sizes[3] / (HID * HID);
    const int G = out_size - N;

    const int* src = eidx;
    const int* dst = eidx + E;

    size_t off = 0;
    auto alloc = [&](size_t bytes) {
        void* p = (char*)d_ws + off;
        off += (bytes + 255) & ~(size_t)255;
        return p;
    };
    int*   cnt     = (int*)alloc((size_t)N * 4);
    int*   row_off = (int*)alloc((size_t)(N + 1) * 4);
    int*   fill    = (int*)alloc((size_t)N * 4);
    int*   col     = (int*)alloc((size_t)E * 4);
    int*   gstart  = (int*)alloc((size_t)(G + 1) * 4);
    int*   bsum    = (int*)alloc(1024 * 4);
    float* sarr    = (float*)alloc((size_t)N * 4);
    float* alpha   = (float*)alloc((size_t)N * 4);
    float* marr    = (float*)alloc((size_t)G * 4);
    float* denom   = (float*)alloc((size_t)G * 4);
    float* gpool   = (float*)alloc((size_t)G * HID * 4);
    u16*   xb      = (u16*)alloc((size_t)N * HID * 2);
    u16*   msgb    = (u16*)alloc((size_t)N * HID * 2);
    u16*   hb1     = (u16*)alloc((size_t)N * HID * 2);
    u16*   hb2     = (u16*)alloc((size_t)N * HID * 2);
    u16*   hidb    = (u16*)alloc((size_t)N * HHALF * 2);
    u16*   WsT     = (u16*)alloc((size_t)L * HID * HID * 2);
    u16*   WnT     = (u16*)alloc((size_t)L * HID * HID * 2);
    u16*   ndW1T   = (u16*)alloc((size_t)HID * HID * 2);  // padded: only first 128 rows valid
    (void)ws_size;

    const int eb = (E + 255) / 256;
    const int nb = (N + 255) / 256;

    // ---- CSR build ----
    hipMemsetAsync(cnt, 0, (size_t)N * 4, stream);
    k_count<<<eb, 256, 0, stream>>>(dst, cnt, E);
    k_scan_block<<<nb, 256, 0, stream>>>(cnt, bsum, N);
    k_scan_top<<<1, 512, 0, stream>>>(bsum, nb);
    k_scan_down<<<nb, 256, 0, stream>>>(cnt, bsum, row_off, N, E);
    hipMemsetAsync(fill, 0, (size_t)N * 4, stream);
    k_scatter<<<eb, 256, 0, stream>>>(src, dst, row_off, fill, col, E);

    // ---- conversions ----
    k_f2b<<<(N * HID / 4 + 255) / 256, 256, 0, stream>>>(x, xb, N * HID / 4);
    k_wt_all<<<(2 * L + 1) * (HID * HID / 256), 256, 0, stream>>>(
        Ws, Wn, nd_W1, WsT, WnT, ndW1T, L);

    // ---- GNN layers ----
    const int gx = (N + 127) / 128;
    const u16* hin = xb;
    u16* hout = hb1;
    for (int l = 0; l < L; ++l) {
        k_agg<<<(N + 3) / 4, 256, 0, stream>>>(hin, row_off, col, msgb, N);
        k_gemm_bf<<<gx, 512, 0, stream>>>(
            hin, WsT + (size_t)l * HID * HID, msgb, WnT + (size_t)l * HID * HID,
            bs + (size_t)l * HID, hout, N, HID);
        hin = hout;
        hout = (hout == hb1) ? hb2 : hb1;
    }
    const u16* h = hin;

    // ---- attention pooling ----
    k_score<<<(N + 3) / 4, 256, 0, stream>>>(h, att_w, att_b, sarr, N);
    k_gstart<<<nb, 256, 0, stream>>>(batch, gstart, N, G);
    k_mdenom<<<G, 256, 0, stream>>>(sarr, gstart, marr, denom);
    k_alpha<<<nb, 256, 0, stream>>>(sarr, batch, marr, denom, alpha, N);
    hipMemsetAsync(gpool, 0, (size_t)G * HID * 4, stream);
    k_pool<<<dim3(G, 16), HID, 0, stream>>>(h, alpha, gstart, gpool);

    // ---- graph head ----
    k_ghead<<<G, HHALF, 0, stream>>>(gpool, ne_W1, ne_b1, ne_W2, ne_b2, out);

    // ---- node head ----
    k_gemm_bf<<<gx, 512, 0, stream>>>(
        h, ndW1T, nullptr, nullptr, nd_b1, hidb, N, HHALF);
    k_ndot<<<(N + 3) / 4, 256, 0, stream>>>(hidb, nd_W2, nd_b2, out + G, N);
}